// Round 11
// baseline (244.263 us; speedup 1.0000x reference)
//
#include <hip/hip_runtime.h>
#include <math.h>

#define D 128
#define NC 32   // privatized histogram copies

typedef __attribute__((ext_vector_type(8))) short bf16x8;
typedef __attribute__((ext_vector_type(4))) float f32x4;

__device__ __forceinline__ unsigned int bf16_round(float f) {
  unsigned int u = __float_as_uint(f);
  return (u + 0x7fffu + ((u >> 16) & 1u)) >> 16;  // RNE
}
__device__ __forceinline__ float bf_lo(unsigned int u) { return __uint_as_float(u << 16); }
__device__ __forceinline__ float bf_hi(unsigned int u) { return __uint_as_float(u & 0xffff0000u); }

// Fused role-split kernel (Bresenham-interleaved so both roles are co-resident):
//  - hist blocks: rank[e] = atomicAdd(partial[c][tgt[e]], 1)   (latency-bound)
//  - pq blocks:   p/q dots + xbh=bf16(x) + (first 64) wt=bf16(W^T)  (BW-bound)
__global__ __launch_bounds__(256) void k_pre(const float* __restrict__ x,
                                             const float* __restrict__ w_pred,
                                             const float* __restrict__ W,
                                             const int* __restrict__ tgt,
                                             float* __restrict__ p, float* __restrict__ q,
                                             unsigned int* __restrict__ xbh,
                                             unsigned short* __restrict__ wt,
                                             int* __restrict__ rank,
                                             int* __restrict__ partial,
                                             int n, int E, int nbHist, int total) {
  int bid = blockIdx.x;
  long long h0 = (long long)bid * nbHist / total;
  long long h1 = (long long)(bid + 1) * nbHist / total;
  if (h1 != h0) {
    // ---- hist role ----
    int e = (int)h0 * 256 + threadIdx.x;
    if (e < E) {
      int t = tgt[e];
      int c = (e >> 8) & (NC - 1);
      rank[e] = atomicAdd(&partial[c * n + t], 1);
    }
    return;
  }
  // ---- pq role ----
  int pqIdx = bid - (int)h1;
  int ptid = pqIdx * 256 + threadIdx.x;
  if (ptid < 16384) {  // W transpose -> bf16 (first 64 pq blocks)
    int col = ptid >> 7, k = ptid & 127;
    wt[col * 128 + k] = (unsigned short)bf16_round(W[k * 128 + col]);
  }
  int wid = ptid >> 6;
  int lane = threadIdx.x & 63;
  if (wid >= n) return;
  float2 xv = ((const float2*)(x + (size_t)wid * D))[lane];
  xbh[(size_t)wid * 64 + lane] = bf16_round(xv.x) | (bf16_round(xv.y) << 16);
  float2 wp = ((const float2*)w_pred)[lane];
  float2 wq = ((const float2*)w_pred)[64 + lane];
  float pp = xv.x * wp.x + xv.y * wp.y;
  float qq = xv.x * wq.x + xv.y * wq.y;
#pragma unroll
  for (int off = 32; off > 0; off >>= 1) {
    pp += __shfl_down(pp, off);
    qq += __shfl_down(qq, off);
  }
  if (lane == 0) { p[wid] = pp; q[wid] = qq; }
}

// scan1 (fused reduce): cnt[t]=sum_c partial[c][t]; block-scan 1024 -> rowptr + bsum
__global__ __launch_bounds__(256) void k_scan1(const int* __restrict__ partial,
                                               int* __restrict__ rowptr,
                                               int* __restrict__ bsum, int n) {
  __shared__ int wsum[4];
  int base = blockIdx.x * 1024 + threadIdx.x * 4;
  int4 v = make_int4(0, 0, 0, 0);
  if (base + 3 < n) {
#pragma unroll
    for (int c = 0; c < NC; ++c) {
      int4 t = *(const int4*)(partial + (size_t)c * n + base);
      v.x += t.x; v.y += t.y; v.z += t.z; v.w += t.w;
    }
  } else {
#pragma unroll
    for (int c = 0; c < NC; ++c) {
      const int* pc = partial + (size_t)c * n;
      if (base + 0 < n) v.x += pc[base + 0];
      if (base + 1 < n) v.y += pc[base + 1];
      if (base + 2 < n) v.z += pc[base + 2];
      if (base + 3 < n) v.w += pc[base + 3];
    }
  }
  int s = v.x + v.y + v.z + v.w;
  int lane = threadIdx.x & 63;
  int wave = threadIdx.x >> 6;
  int incl = s;
#pragma unroll
  for (int off = 1; off < 64; off <<= 1) {
    int t = __shfl_up(incl, off);
    if (lane >= off) incl += t;
  }
  if (lane == 63) wsum[wave] = incl;
  __syncthreads();
  int woff = 0;
#pragma unroll
  for (int w = 0; w < 4; ++w) if (w < wave) woff += wsum[w];
  int excl = woff + incl - s;
  if (base + 0 < n) rowptr[base + 0] = excl;
  if (base + 1 < n) rowptr[base + 1] = excl + v.x;
  if (base + 2 < n) rowptr[base + 2] = excl + v.x + v.y;
  if (base + 3 < n) rowptr[base + 3] = excl + v.x + v.y + v.z;
  if (threadIdx.x == 255) bsum[blockIdx.x] = woff + incl;
}

// cursors (scan2 fused): wave 0 scans bsum; finalize rowptr; cursor[c][t] bases
__global__ __launch_bounds__(256) void k_cursors(int* __restrict__ rowptr,
                                                 const int* __restrict__ bsum,
                                                 const int* __restrict__ partial,
                                                 int* __restrict__ cursor,
                                                 int n, int E, int nb) {
  __shared__ int bpre_s[64];
  if (threadIdx.x < 64) {
    int lane = threadIdx.x;
    int v = (lane < nb) ? bsum[lane] : 0;
    int incl = v;
#pragma unroll
    for (int off = 1; off < 64; off <<= 1) {
      int t = __shfl_up(incl, off);
      if (lane >= off) incl += t;
    }
    bpre_s[lane] = incl - v;
  }
  __syncthreads();
  int t = blockIdx.x * blockDim.x + threadIdx.x;
  if (t < n) {
    int r = rowptr[t] + bpre_s[t >> 10];
    rowptr[t] = r;
#pragma unroll
    for (int c = 0; c < NC; ++c) {
      cursor[c * n + t] = r;
      r += partial[c * n + t];
    }
  }
  if (t == 0) rowptr[n] = E;
}

// fill (NO atomics): ew = sigmoid(p[s]+q[t]+b); epair[cursor_base+rank] = (s, ew)
__global__ __launch_bounds__(256) void k_fill(const int* __restrict__ src,
                                              const int* __restrict__ tgt,
                                              const int* __restrict__ rank,
                                              const int* __restrict__ cursor,
                                              const float* __restrict__ p,
                                              const float* __restrict__ q,
                                              const float* __restrict__ b_pred,
                                              int2* __restrict__ epair, int E, int n) {
  int e = blockIdx.x * blockDim.x + threadIdx.x;
  if (e >= E) return;
  int s = src[e], t = tgt[e];
  int c = (e >> 8) & (NC - 1);
  int pos = cursor[c * n + t] + rank[e];
  float z = p[s] + q[t] + b_pred[0];
  float w = 1.0f / (1.0f + expf(-z));
  epair[pos] = make_int2(s, __float_as_int(w));
}

// MFMA GEMM + fused dis: per wave, 4 lanes/row segmented-sum epair -> dis in
// register, then xwh = bf16( dis[row] * (xbh @ W) ). Also writes dis.
__global__ __launch_bounds__(256) void k_gemm_mfma(const short* __restrict__ xbh,
                                                   const short* __restrict__ wt,
                                                   const int* __restrict__ rowptr,
                                                   const int2* __restrict__ epair,
                                                   float* __restrict__ dis,
                                                   unsigned int* __restrict__ xwh, int n) {
  __shared__ float cbuf[4][16 * 128];  // 32 KB
  int wave = threadIdx.x >> 6;
  int lane = threadIdx.x & 63;
  int row0 = blockIdx.x * 64 + wave * 16;

  // ---- dis for this wave's 16 rows (4 lanes per row) ----
  int rr = lane >> 2, jj = lane & 3;
  int grow = row0 + rr;
  float dv = 0.0f;
  if (grow < n) {
    int beg = rowptr[grow], end = rowptr[grow + 1];
    float sum = 0.0f;
    for (int j = beg + jj; j < end; j += 4) sum += __int_as_float(epair[j].y);
    sum += __shfl_xor(sum, 1);
    sum += __shfl_xor(sum, 2);
    float d = 1.0f + sum;
    dv = (d > 0.0f) ? rsqrtf(d) : 0.0f;
    if (jj == 0) dis[grow] = dv;
  }

  // ---- MFMA ----
  int rA = lane & 15, quad = lane >> 4;
  f32x4 acc[8];
#pragma unroll
  for (int cb = 0; cb < 8; ++cb) acc[cb] = (f32x4){0.f, 0.f, 0.f, 0.f};

  const short* arow = xbh + (size_t)(row0 + rA) * 128 + quad * 8;
  bool arow_ok = (row0 + rA) < n;
#pragma unroll
  for (int kk = 0; kk < 4; ++kk) {
    bf16x8 a;
    if (arow_ok) a = *(const bf16x8*)(arow + kk * 32);
    else a = (bf16x8){0, 0, 0, 0, 0, 0, 0, 0};
#pragma unroll
    for (int cb = 0; cb < 8; ++cb) {
      bf16x8 bf = *(const bf16x8*)(wt + (size_t)(cb * 16 + rA) * 128 + kk * 32 + quad * 8);
      acc[cb] = __builtin_amdgcn_mfma_f32_16x16x32_bf16(a, bf, acc[cb], 0, 0, 0);
    }
  }

  // C/D layout: col = cb*16 + (lane&15), row = quad*4 + reg
#pragma unroll
  for (int cb = 0; cb < 8; ++cb)
#pragma unroll
    for (int r = 0; r < 4; ++r)
      cbuf[wave][(quad * 4 + r) * 128 + cb * 16 + rA] = acc[cb][r];
  __syncthreads();

  int ch = jj * 32;                // col chunk of 32 (jj = lane&3)
  if (grow < n) {
    const float* cr = &cbuf[wave][rr * 128 + ch];
#pragma unroll
    for (int g = 0; g < 2; ++g) {  // 2 x 16 cols -> 2 x uint4
      uint4 o;
      o.x = bf16_round(cr[g * 16 + 0] * dv)  | (bf16_round(cr[g * 16 + 1] * dv) << 16);
      o.y = bf16_round(cr[g * 16 + 2] * dv)  | (bf16_round(cr[g * 16 + 3] * dv) << 16);
      o.z = bf16_round(cr[g * 16 + 4] * dv)  | (bf16_round(cr[g * 16 + 5] * dv) << 16);
      o.w = bf16_round(cr[g * 16 + 6] * dv)  | (bf16_round(cr[g * 16 + 7] * dv) << 16);
      uint4 o2;
      o2.x = bf16_round(cr[g * 16 + 8] * dv)  | (bf16_round(cr[g * 16 + 9] * dv) << 16);
      o2.y = bf16_round(cr[g * 16 + 10] * dv) | (bf16_round(cr[g * 16 + 11] * dv) << 16);
      o2.z = bf16_round(cr[g * 16 + 12] * dv) | (bf16_round(cr[g * 16 + 13] * dv) << 16);
      o2.w = bf16_round(cr[g * 16 + 14] * dv) | (bf16_round(cr[g * 16 + 15] * dv) << 16);
      *(uint4*)(xwh + (size_t)grow * 64 + (ch >> 1) + g * 8)     = o;
      *(uint4*)(xwh + (size_t)grow * 64 + (ch >> 1) + g * 8 + 4) = o2;
    }
  }
}

// Column-quarter gather: one wave per (node, quarter); quarter-major block order
// keeps each phase on a 3.2 MB xwh slice (fits per-XCD L2). lane = (rg in
// [0,16) edge slot, cj in [0,4) 16B chunk): one wave-load covers 16 edges.
__global__ __launch_bounds__(256) void k_gather(const int* __restrict__ rowptr,
                                                const int2* __restrict__ epair,
                                                const uint4* __restrict__ xwh4,
                                                const float* __restrict__ dis,
                                                const float* __restrict__ b,
                                                float* __restrict__ out, int n) {
  int gw = blockIdx.x * 4 + (threadIdx.x >> 6);  // global wave id in [0, 4n)
  int lane = threadIdx.x & 63;
  int qtr = gw / n;          // quarter-major
  int wid = gw - qtr * n;    // node
  if (qtr >= 4) return;
  int cj = lane & 3;         // 16B chunk within the 64B quarter-row
  int rg = lane >> 2;        // edge slot 0..15
  int beg = rowptr[wid], end = rowptr[wid + 1];
  const uint4* slice = xwh4 + qtr * 4 + cj;  // + s*16 per row

  float acc[8];
  if (rg == 0) {  // self-loop term, counted once per quarter
    uint4 v = slice[(size_t)wid * 16];
    acc[0] = bf_lo(v.x); acc[1] = bf_hi(v.x);
    acc[2] = bf_lo(v.y); acc[3] = bf_hi(v.y);
    acc[4] = bf_lo(v.z); acc[5] = bf_hi(v.z);
    acc[6] = bf_lo(v.w); acc[7] = bf_hi(v.w);
  } else {
#pragma unroll
    for (int i = 0; i < 8; ++i) acc[i] = 0.0f;
  }

  for (int j0 = beg; j0 < end; j0 += 64) {
    int m = end - j0; if (m > 64) m = 64;
    int sl = 0; float cl = 0.0f;
    if (lane < m) {
      int2 pr = epair[j0 + lane];
      sl = pr.x; cl = __int_as_float(pr.y);
    }
    for (int k = 0; k < m; k += 16) {
      int idx = k + rg;
      int s = __shfl(sl, idx);
      float c = __shfl(cl, idx);
      if (idx >= m) { s = 0; c = 0.0f; }
      uint4 v = slice[(size_t)s * 16];
      acc[0] = fmaf(c, bf_lo(v.x), acc[0]);
      acc[1] = fmaf(c, bf_hi(v.x), acc[1]);
      acc[2] = fmaf(c, bf_lo(v.y), acc[2]);
      acc[3] = fmaf(c, bf_hi(v.y), acc[3]);
      acc[4] = fmaf(c, bf_lo(v.z), acc[4]);
      acc[5] = fmaf(c, bf_hi(v.z), acc[5]);
      acc[6] = fmaf(c, bf_lo(v.w), acc[6]);
      acc[7] = fmaf(c, bf_hi(v.w), acc[7]);
    }
  }

#pragma unroll
  for (int i = 0; i < 8; ++i) {
    acc[i] += __shfl_xor(acc[i], 4);
    acc[i] += __shfl_xor(acc[i], 8);
    acc[i] += __shfl_xor(acc[i], 16);
    acc[i] += __shfl_xor(acc[i], 32);
  }

  if (rg == 0) {
    float dt = dis[wid];
    float4 b0 = ((const float4*)b)[qtr * 8 + cj * 2];
    float4 b1 = ((const float4*)b)[qtr * 8 + cj * 2 + 1];
    float4 o0, o1;
    o0.x = fmaf(dt, acc[0], b0.x); o0.y = fmaf(dt, acc[1], b0.y);
    o0.z = fmaf(dt, acc[2], b0.z); o0.w = fmaf(dt, acc[3], b0.w);
    o1.x = fmaf(dt, acc[4], b1.x); o1.y = fmaf(dt, acc[5], b1.y);
    o1.z = fmaf(dt, acc[6], b1.z); o1.w = fmaf(dt, acc[7], b1.w);
    ((float4*)out)[(size_t)wid * 32 + qtr * 8 + cj * 2]     = o0;
    ((float4*)out)[(size_t)wid * 32 + qtr * 8 + cj * 2 + 1] = o1;
  }
}

extern "C" void kernel_launch(void* const* d_in, const int* in_sizes, int n_in,
                              void* d_out, int out_size, void* d_ws, size_t ws_size,
                              hipStream_t stream) {
  const float* x      = (const float*)d_in[0];
  const int*   ei     = (const int*)d_in[1];
  const float* W      = (const float*)d_in[2];
  const float* b      = (const float*)d_in[3];
  const float* w_pred = (const float*)d_in[4];
  const float* b_pred = (const float*)d_in[5];

  int n = in_sizes[0] / D;
  int E = in_sizes[1] / 2;
  const int* src = ei;       // edge_index[0]
  const int* tgt = ei + E;   // edge_index[1]

  float* out = (float*)d_out;
  float* ws  = (float*)d_ws;
  // workspace layout (4B words)
  unsigned int* xwh = (unsigned int*)ws;           // n*64 (bf16 pairs)
  unsigned int* xbh = xwh + (size_t)n * 64;        // n*64 (bf16 pairs of x)
  float* p       = (float*)(xbh + (size_t)n * 64); // n
  float* q       = p + n;                          // n
  float* dis     = q + n;                          // n
  int2*  epair   = (int2*)(dis + n);               // E pairs (2E words)
  int*   rank    = (int*)(epair + E);              // E
  int*   partial = rank + E;                       // NC*n
  int*   cursor  = partial + (size_t)NC * n;       // NC*n
  int*   rowptr  = cursor + (size_t)NC * n;        // n+1
  int*   bsum    = rowptr + n + 1;                 // 64
  unsigned short* wt = (unsigned short*)(bsum + 64);  // 16384 shorts

  int nb = (n + 1023) / 1024;     // scan blocks (<=64 for n<=65536)
  int nbPq = (n + 3) / 4;
  int nbHist = (E + 255) / 256;
  int total = nbPq + nbHist;

  (void)hipMemsetAsync(partial, 0, (size_t)NC * n * sizeof(int), stream);
  k_pre<<<total, 256, 0, stream>>>(x, w_pred, W, tgt, p, q, xbh, wt, rank, partial,
                                   n, E, nbHist, total);
  k_scan1<<<nb, 256, 0, stream>>>(partial, rowptr, bsum, n);
  k_cursors<<<(n + 255) / 256, 256, 0, stream>>>(rowptr, bsum, partial, cursor, n, E, nb);
  k_fill<<<(E + 255) / 256, 256, 0, stream>>>(src, tgt, rank, cursor, p, q, b_pred, epair, E, n);
  k_gemm_mfma<<<(n + 63) / 64, 256, 0, stream>>>((const short*)xbh, (const short*)wt,
                                                 rowptr, epair, dis, xwh, n);
  k_gather<<<n, 256, 0, stream>>>(rowptr, epair, (const uint4*)xwh, dis, b, out, n);
}

// Round 12
// 196.864 us; speedup vs baseline: 1.2408x; 1.2408x over previous
//
#include <hip/hip_runtime.h>
#include <math.h>

#define D 128
#define NC 32   // privatized histogram copies

typedef __attribute__((ext_vector_type(8))) short bf16x8;
typedef __attribute__((ext_vector_type(4))) float f32x4;

__device__ __forceinline__ unsigned int bf16_round(float f) {
  unsigned int u = __float_as_uint(f);
  return (u + 0x7fffu + ((u >> 16) & 1u)) >> 16;  // RNE
}
__device__ __forceinline__ float bf_lo(unsigned int u) { return __uint_as_float(u << 16); }
__device__ __forceinline__ float bf_hi(unsigned int u) { return __uint_as_float(u & 0xffff0000u); }

// Fused role-split kernel (Bresenham-interleaved so both roles are co-resident):
//  - hist blocks: rank[e] = atomicAdd(partial[c][tgt[e]], 1)   (latency-bound)
//  - pq blocks:   p/q dots + xbh=bf16(x) + (first 64) wt=bf16(W^T)  (BW-bound)
__global__ __launch_bounds__(256) void k_pre(const float* __restrict__ x,
                                             const float* __restrict__ w_pred,
                                             const float* __restrict__ W,
                                             const int* __restrict__ tgt,
                                             float* __restrict__ p, float* __restrict__ q,
                                             unsigned int* __restrict__ xbh,
                                             unsigned short* __restrict__ wt,
                                             int* __restrict__ rank,
                                             int* __restrict__ partial,
                                             int n, int E, int nbHist, int total) {
  int bid = blockIdx.x;
  long long h0 = (long long)bid * nbHist / total;
  long long h1 = (long long)(bid + 1) * nbHist / total;
  if (h1 != h0) {
    // ---- hist role ----
    int e = (int)h0 * 256 + threadIdx.x;
    if (e < E) {
      int t = tgt[e];
      int c = (e >> 8) & (NC - 1);
      rank[e] = atomicAdd(&partial[c * n + t], 1);
    }
    return;
  }
  // ---- pq role ----
  int pqIdx = bid - (int)h1;
  int ptid = pqIdx * 256 + threadIdx.x;
  if (ptid < 16384) {  // W transpose -> bf16 (first 64 pq blocks)
    int col = ptid >> 7, k = ptid & 127;
    wt[col * 128 + k] = (unsigned short)bf16_round(W[k * 128 + col]);
  }
  int wid = ptid >> 6;
  int lane = threadIdx.x & 63;
  if (wid >= n) return;
  float2 xv = ((const float2*)(x + (size_t)wid * D))[lane];
  xbh[(size_t)wid * 64 + lane] = bf16_round(xv.x) | (bf16_round(xv.y) << 16);
  float2 wp = ((const float2*)w_pred)[lane];
  float2 wq = ((const float2*)w_pred)[64 + lane];
  float pp = xv.x * wp.x + xv.y * wp.y;
  float qq = xv.x * wq.x + xv.y * wq.y;
#pragma unroll
  for (int off = 32; off > 0; off >>= 1) {
    pp += __shfl_down(pp, off);
    qq += __shfl_down(qq, off);
  }
  if (lane == 0) { p[wid] = pp; q[wid] = qq; }
}

// scan1 (fused reduce): cnt[t]=sum_c partial[c][t]; block-scan 1024 -> rowptr + bsum
__global__ __launch_bounds__(256) void k_scan1(const int* __restrict__ partial,
                                               int* __restrict__ rowptr,
                                               int* __restrict__ bsum, int n) {
  __shared__ int wsum[4];
  int base = blockIdx.x * 1024 + threadIdx.x * 4;
  int4 v = make_int4(0, 0, 0, 0);
  if (base + 3 < n) {
#pragma unroll
    for (int c = 0; c < NC; ++c) {
      int4 t = *(const int4*)(partial + (size_t)c * n + base);
      v.x += t.x; v.y += t.y; v.z += t.z; v.w += t.w;
    }
  } else {
#pragma unroll
    for (int c = 0; c < NC; ++c) {
      const int* pc = partial + (size_t)c * n;
      if (base + 0 < n) v.x += pc[base + 0];
      if (base + 1 < n) v.y += pc[base + 1];
      if (base + 2 < n) v.z += pc[base + 2];
      if (base + 3 < n) v.w += pc[base + 3];
    }
  }
  int s = v.x + v.y + v.z + v.w;
  int lane = threadIdx.x & 63;
  int wave = threadIdx.x >> 6;
  int incl = s;
#pragma unroll
  for (int off = 1; off < 64; off <<= 1) {
    int t = __shfl_up(incl, off);
    if (lane >= off) incl += t;
  }
  if (lane == 63) wsum[wave] = incl;
  __syncthreads();
  int woff = 0;
#pragma unroll
  for (int w = 0; w < 4; ++w) if (w < wave) woff += wsum[w];
  int excl = woff + incl - s;
  if (base + 0 < n) rowptr[base + 0] = excl;
  if (base + 1 < n) rowptr[base + 1] = excl + v.x;
  if (base + 2 < n) rowptr[base + 2] = excl + v.x + v.y;
  if (base + 3 < n) rowptr[base + 3] = excl + v.x + v.y + v.z;
  if (threadIdx.x == 255) bsum[blockIdx.x] = woff + incl;
}

// cursors (scan2 fused): wave 0 scans bsum; finalize rowptr; cursor[c][t] bases
__global__ __launch_bounds__(256) void k_cursors(int* __restrict__ rowptr,
                                                 const int* __restrict__ bsum,
                                                 const int* __restrict__ partial,
                                                 int* __restrict__ cursor,
                                                 int n, int E, int nb) {
  __shared__ int bpre_s[64];
  if (threadIdx.x < 64) {
    int lane = threadIdx.x;
    int v = (lane < nb) ? bsum[lane] : 0;
    int incl = v;
#pragma unroll
    for (int off = 1; off < 64; off <<= 1) {
      int t = __shfl_up(incl, off);
      if (lane >= off) incl += t;
    }
    bpre_s[lane] = incl - v;
  }
  __syncthreads();
  int t = blockIdx.x * blockDim.x + threadIdx.x;
  if (t < n) {
    int r = rowptr[t] + bpre_s[t >> 10];
    rowptr[t] = r;
#pragma unroll
    for (int c = 0; c < NC; ++c) {
      cursor[c * n + t] = r;
      r += partial[c * n + t];
    }
  }
  if (t == 0) rowptr[n] = E;
}

// fill (NO atomics): ew = sigmoid(p[s]+q[t]+b);
// edata[cursor_base+rank] = (src:u16 | bf16(ew)<<16)  -- 4B packed record
__global__ __launch_bounds__(256) void k_fill(const int* __restrict__ src,
                                              const int* __restrict__ tgt,
                                              const int* __restrict__ rank,
                                              const int* __restrict__ cursor,
                                              const float* __restrict__ p,
                                              const float* __restrict__ q,
                                              const float* __restrict__ b_pred,
                                              unsigned int* __restrict__ edata,
                                              int E, int n) {
  int e = blockIdx.x * blockDim.x + threadIdx.x;
  if (e >= E) return;
  int s = src[e], t = tgt[e];
  int c = (e >> 8) & (NC - 1);
  int pos = cursor[c * n + t] + rank[e];
  float z = p[s] + q[t] + b_pred[0];
  float w = 1.0f / (1.0f + expf(-z));
  edata[pos] = (unsigned int)s | (bf16_round(w) << 16);  // n < 65536 fits u16
}

// MFMA GEMM + fused dis: per wave, 4 lanes/row segmented-sum edata -> dis in
// register, then xwh = bf16( dis[row] * (xbh @ W) ). Also writes dis.
__global__ __launch_bounds__(256) void k_gemm_mfma(const short* __restrict__ xbh,
                                                   const short* __restrict__ wt,
                                                   const int* __restrict__ rowptr,
                                                   const unsigned int* __restrict__ edata,
                                                   float* __restrict__ dis,
                                                   unsigned int* __restrict__ xwh, int n) {
  __shared__ float cbuf[4][16 * 128];  // 32 KB
  int wave = threadIdx.x >> 6;
  int lane = threadIdx.x & 63;
  int row0 = blockIdx.x * 64 + wave * 16;

  // ---- dis for this wave's 16 rows (4 lanes per row) ----
  int rr = lane >> 2, jj = lane & 3;
  int grow = row0 + rr;
  float dv = 0.0f;
  if (grow < n) {
    int beg = rowptr[grow], end = rowptr[grow + 1];
    float sum = 0.0f;
    for (int j = beg + jj; j < end; j += 4) sum += bf_hi(edata[j]);
    sum += __shfl_xor(sum, 1);
    sum += __shfl_xor(sum, 2);
    float d = 1.0f + sum;
    dv = (d > 0.0f) ? rsqrtf(d) : 0.0f;
    if (jj == 0) dis[grow] = dv;
  }

  // ---- MFMA ----
  int rA = lane & 15, quad = lane >> 4;
  f32x4 acc[8];
#pragma unroll
  for (int cb = 0; cb < 8; ++cb) acc[cb] = (f32x4){0.f, 0.f, 0.f, 0.f};

  const short* arow = xbh + (size_t)(row0 + rA) * 128 + quad * 8;
  bool arow_ok = (row0 + rA) < n;
#pragma unroll
  for (int kk = 0; kk < 4; ++kk) {
    bf16x8 a;
    if (arow_ok) a = *(const bf16x8*)(arow + kk * 32);
    else a = (bf16x8){0, 0, 0, 0, 0, 0, 0, 0};
#pragma unroll
    for (int cb = 0; cb < 8; ++cb) {
      bf16x8 bf = *(const bf16x8*)(wt + (size_t)(cb * 16 + rA) * 128 + kk * 32 + quad * 8);
      acc[cb] = __builtin_amdgcn_mfma_f32_16x16x32_bf16(a, bf, acc[cb], 0, 0, 0);
    }
  }

  // C/D layout: col = cb*16 + (lane&15), row = quad*4 + reg
#pragma unroll
  for (int cb = 0; cb < 8; ++cb)
#pragma unroll
    for (int r = 0; r < 4; ++r)
      cbuf[wave][(quad * 4 + r) * 128 + cb * 16 + rA] = acc[cb][r];
  __syncthreads();

  int ch = jj * 32;                // col chunk of 32 (jj = lane&3)
  if (grow < n) {
    const float* cr = &cbuf[wave][rr * 128 + ch];
#pragma unroll
    for (int g = 0; g < 2; ++g) {  // 2 x 16 cols -> 2 x uint4
      uint4 o;
      o.x = bf16_round(cr[g * 16 + 0] * dv)  | (bf16_round(cr[g * 16 + 1] * dv) << 16);
      o.y = bf16_round(cr[g * 16 + 2] * dv)  | (bf16_round(cr[g * 16 + 3] * dv) << 16);
      o.z = bf16_round(cr[g * 16 + 4] * dv)  | (bf16_round(cr[g * 16 + 5] * dv) << 16);
      o.w = bf16_round(cr[g * 16 + 6] * dv)  | (bf16_round(cr[g * 16 + 7] * dv) << 16);
      uint4 o2;
      o2.x = bf16_round(cr[g * 16 + 8] * dv)  | (bf16_round(cr[g * 16 + 9] * dv) << 16);
      o2.y = bf16_round(cr[g * 16 + 10] * dv) | (bf16_round(cr[g * 16 + 11] * dv) << 16);
      o2.z = bf16_round(cr[g * 16 + 12] * dv) | (bf16_round(cr[g * 16 + 13] * dv) << 16);
      o2.w = bf16_round(cr[g * 16 + 14] * dv) | (bf16_round(cr[g * 16 + 15] * dv) << 16);
      *(uint4*)(xwh + (size_t)grow * 64 + (ch >> 1) + g * 8)     = o;
      *(uint4*)(xwh + (size_t)grow * 64 + (ch >> 1) + g * 8 + 4) = o2;
    }
  }
}

// One wave per node; lane = (rg in [0,4), cj in [0,16)). Each lane loads a
// full uint4 (8 bf16 cols) of the source row for edge k+rg: one load covers
// 4 source rows (1 KB/wave). shfl_xor folds the 4 rg partials.
__global__ __launch_bounds__(256) void k_gather(const int* __restrict__ rowptr,
                                                const unsigned int* __restrict__ edata,
                                                const uint4* __restrict__ xwh4,
                                                const float* __restrict__ dis,
                                                const float* __restrict__ b,
                                                float* __restrict__ out, int n) {
  int wid = (blockIdx.x * blockDim.x + threadIdx.x) >> 6;
  int lane = threadIdx.x & 63;
  if (wid >= n) return;
  int cj = lane & 15;
  int rg = lane >> 4;
  int beg = rowptr[wid], end = rowptr[wid + 1];

  float acc[8];
  if (rg == 0) {  // self-loop term, counted once
    uint4 v = xwh4[(size_t)wid * 16 + cj];
    acc[0] = bf_lo(v.x); acc[1] = bf_hi(v.x);
    acc[2] = bf_lo(v.y); acc[3] = bf_hi(v.y);
    acc[4] = bf_lo(v.z); acc[5] = bf_hi(v.z);
    acc[6] = bf_lo(v.w); acc[7] = bf_hi(v.w);
  } else {
#pragma unroll
    for (int i = 0; i < 8; ++i) acc[i] = 0.0f;
  }

  for (int j0 = beg; j0 < end; j0 += 64) {
    int m = end - j0; if (m > 64) m = 64;
    unsigned int wl = 0;
    if (lane < m) wl = edata[j0 + lane];
    for (int k = 0; k < m; k += 4) {
      int idx = k + rg;
      unsigned int w = (unsigned int)__shfl((int)wl, idx);
      if (idx >= m) w = 0;
      int s = (int)(w & 0xffffu);
      float c = bf_hi(w);
      uint4 v = xwh4[(size_t)s * 16 + cj];
      acc[0] = fmaf(c, bf_lo(v.x), acc[0]);
      acc[1] = fmaf(c, bf_hi(v.x), acc[1]);
      acc[2] = fmaf(c, bf_lo(v.y), acc[2]);
      acc[3] = fmaf(c, bf_hi(v.y), acc[3]);
      acc[4] = fmaf(c, bf_lo(v.z), acc[4]);
      acc[5] = fmaf(c, bf_hi(v.z), acc[5]);
      acc[6] = fmaf(c, bf_lo(v.w), acc[6]);
      acc[7] = fmaf(c, bf_hi(v.w), acc[7]);
    }
  }

#pragma unroll
  for (int i = 0; i < 8; ++i) {
    acc[i] += __shfl_xor(acc[i], 16);
    acc[i] += __shfl_xor(acc[i], 32);
  }

  if (rg == 0) {
    float dt = dis[wid];
    float4 b0 = ((const float4*)b)[cj * 2];
    float4 b1 = ((const float4*)b)[cj * 2 + 1];
    float4 o0, o1;
    o0.x = fmaf(dt, acc[0], b0.x); o0.y = fmaf(dt, acc[1], b0.y);
    o0.z = fmaf(dt, acc[2], b0.z); o0.w = fmaf(dt, acc[3], b0.w);
    o1.x = fmaf(dt, acc[4], b1.x); o1.y = fmaf(dt, acc[5], b1.y);
    o1.z = fmaf(dt, acc[6], b1.z); o1.w = fmaf(dt, acc[7], b1.w);
    ((float4*)out)[(size_t)wid * 32 + cj * 2] = o0;
    ((float4*)out)[(size_t)wid * 32 + cj * 2 + 1] = o1;
  }
}

extern "C" void kernel_launch(void* const* d_in, const int* in_sizes, int n_in,
                              void* d_out, int out_size, void* d_ws, size_t ws_size,
                              hipStream_t stream) {
  const float* x      = (const float*)d_in[0];
  const int*   ei     = (const int*)d_in[1];
  const float* W      = (const float*)d_in[2];
  const float* b      = (const float*)d_in[3];
  const float* w_pred = (const float*)d_in[4];
  const float* b_pred = (const float*)d_in[5];

  int n = in_sizes[0] / D;
  int E = in_sizes[1] / 2;
  const int* src = ei;       // edge_index[0]
  const int* tgt = ei + E;   // edge_index[1]

  float* out = (float*)d_out;
  float* ws  = (float*)d_ws;
  // workspace layout (4B words)
  unsigned int* xwh = (unsigned int*)ws;           // n*64 (bf16 pairs)
  unsigned int* xbh = xwh + (size_t)n * 64;        // n*64 (bf16 pairs of x)
  float* p       = (float*)(xbh + (size_t)n * 64); // n
  float* q       = p + n;                          // n
  float* dis     = q + n;                          // n
  unsigned int* edata = (unsigned int*)(dis + n);  // E packed (src|ew)
  int*   rank    = (int*)(edata + E);              // E
  int*   partial = rank + E;                       // NC*n
  int*   cursor  = partial + (size_t)NC * n;       // NC*n
  int*   rowptr  = cursor + (size_t)NC * n;        // n+1
  int*   bsum    = rowptr + n + 1;                 // 64
  unsigned short* wt = (unsigned short*)(bsum + 64);  // 16384 shorts

  int nb = (n + 1023) / 1024;     // scan blocks (<=64 for n<=65536)
  int nbPq = (n + 3) / 4;
  int nbHist = (E + 255) / 256;
  int total = nbPq + nbHist;

  (void)hipMemsetAsync(partial, 0, (size_t)NC * n * sizeof(int), stream);
  k_pre<<<total, 256, 0, stream>>>(x, w_pred, W, tgt, p, q, xbh, wt, rank, partial,
                                   n, E, nbHist, total);
  k_scan1<<<nb, 256, 0, stream>>>(partial, rowptr, bsum, n);
  k_cursors<<<(n + 255) / 256, 256, 0, stream>>>(rowptr, bsum, partial, cursor, n, E, nb);
  k_fill<<<(E + 255) / 256, 256, 0, stream>>>(src, tgt, rank, cursor, p, q, b_pred, edata, E, n);
  k_gemm_mfma<<<(n + 63) / 64, 256, 0, stream>>>((const short*)xbh, (const short*)wt,
                                                 rowptr, edata, dis, xwh, n);
  k_gather<<<(n + 3) / 4, 256, 0, stream>>>(rowptr, edata, (const uint4*)xwh, dis, b, out, n);
}

// Round 13
// 192.834 us; speedup vs baseline: 1.2667x; 1.0209x over previous
//
#include <hip/hip_runtime.h>
#include <math.h>

#define D 128
#define NC 32   // privatized histogram copies

typedef __attribute__((ext_vector_type(8))) short bf16x8;
typedef __attribute__((ext_vector_type(4))) float f32x4;

__device__ __forceinline__ unsigned int bf16_round(float f) {
  unsigned int u = __float_as_uint(f);
  return (u + 0x7fffu + ((u >> 16) & 1u)) >> 16;  // RNE
}
__device__ __forceinline__ float bf_lo(unsigned int u) { return __uint_as_float(u << 16); }
__device__ __forceinline__ float bf_hi(unsigned int u) { return __uint_as_float(u & 0xffff0000u); }

// Fused role-split kernel (Bresenham-interleaved so both roles are co-resident):
//  - hist blocks: rank[e] = atomicAdd(partial[c][tgt[e]], 1)   (latency-bound)
//  - pq blocks:   p/q dots + xbh=bf16(x) + (first 64) wt=bf16(W^T)  (BW-bound)
__global__ __launch_bounds__(256) void k_pre(const float* __restrict__ x,
                                             const float* __restrict__ w_pred,
                                             const float* __restrict__ W,
                                             const int* __restrict__ tgt,
                                             float* __restrict__ p, float* __restrict__ q,
                                             unsigned int* __restrict__ xbh,
                                             unsigned short* __restrict__ wt,
                                             int* __restrict__ rank,
                                             int* __restrict__ partial,
                                             int n, int E, int nbHist, int total) {
  int bid = blockIdx.x;
  long long h0 = (long long)bid * nbHist / total;
  long long h1 = (long long)(bid + 1) * nbHist / total;
  if (h1 != h0) {
    // ---- hist role ----
    int e = (int)h0 * 256 + threadIdx.x;
    if (e < E) {
      int t = tgt[e];
      int c = (e >> 8) & (NC - 1);
      rank[e] = atomicAdd(&partial[c * n + t], 1);
    }
    return;
  }
  // ---- pq role ----
  int pqIdx = bid - (int)h1;
  int ptid = pqIdx * 256 + threadIdx.x;
  if (ptid < 16384) {  // W transpose -> bf16 (first 64 pq blocks)
    int col = ptid >> 7, k = ptid & 127;
    wt[col * 128 + k] = (unsigned short)bf16_round(W[k * 128 + col]);
  }
  int wid = ptid >> 6;
  int lane = threadIdx.x & 63;
  if (wid >= n) return;
  float2 xv = ((const float2*)(x + (size_t)wid * D))[lane];
  xbh[(size_t)wid * 64 + lane] = bf16_round(xv.x) | (bf16_round(xv.y) << 16);
  float2 wp = ((const float2*)w_pred)[lane];
  float2 wq = ((const float2*)w_pred)[64 + lane];
  float pp = xv.x * wp.x + xv.y * wp.y;
  float qq = xv.x * wq.x + xv.y * wq.y;
#pragma unroll
  for (int off = 32; off > 0; off >>= 1) {
    pp += __shfl_down(pp, off);
    qq += __shfl_down(qq, off);
  }
  if (lane == 0) { p[wid] = pp; q[wid] = qq; }
}

// scan1 (fused reduce): cnt[t]=sum_c partial[c][t]; block-scan 1024 -> rowptr + bsum
__global__ __launch_bounds__(256) void k_scan1(const int* __restrict__ partial,
                                               int* __restrict__ rowptr,
                                               int* __restrict__ bsum, int n) {
  __shared__ int wsum[4];
  int base = blockIdx.x * 1024 + threadIdx.x * 4;
  int4 v = make_int4(0, 0, 0, 0);
  if (base + 3 < n) {
#pragma unroll
    for (int c = 0; c < NC; ++c) {
      int4 t = *(const int4*)(partial + (size_t)c * n + base);
      v.x += t.x; v.y += t.y; v.z += t.z; v.w += t.w;
    }
  } else {
#pragma unroll
    for (int c = 0; c < NC; ++c) {
      const int* pc = partial + (size_t)c * n;
      if (base + 0 < n) v.x += pc[base + 0];
      if (base + 1 < n) v.y += pc[base + 1];
      if (base + 2 < n) v.z += pc[base + 2];
      if (base + 3 < n) v.w += pc[base + 3];
    }
  }
  int s = v.x + v.y + v.z + v.w;
  int lane = threadIdx.x & 63;
  int wave = threadIdx.x >> 6;
  int incl = s;
#pragma unroll
  for (int off = 1; off < 64; off <<= 1) {
    int t = __shfl_up(incl, off);
    if (lane >= off) incl += t;
  }
  if (lane == 63) wsum[wave] = incl;
  __syncthreads();
  int woff = 0;
#pragma unroll
  for (int w = 0; w < 4; ++w) if (w < wave) woff += wsum[w];
  int excl = woff + incl - s;
  if (base + 0 < n) rowptr[base + 0] = excl;
  if (base + 1 < n) rowptr[base + 1] = excl + v.x;
  if (base + 2 < n) rowptr[base + 2] = excl + v.x + v.y;
  if (base + 3 < n) rowptr[base + 3] = excl + v.x + v.y + v.z;
  if (threadIdx.x == 255) bsum[blockIdx.x] = woff + incl;
}

// cursors (scan2 fused): wave 0 scans bsum; finalize rowptr; cursor[c][t] bases
__global__ __launch_bounds__(256) void k_cursors(int* __restrict__ rowptr,
                                                 const int* __restrict__ bsum,
                                                 const int* __restrict__ partial,
                                                 int* __restrict__ cursor,
                                                 int n, int E, int nb) {
  __shared__ int bpre_s[64];
  if (threadIdx.x < 64) {
    int lane = threadIdx.x;
    int v = (lane < nb) ? bsum[lane] : 0;
    int incl = v;
#pragma unroll
    for (int off = 1; off < 64; off <<= 1) {
      int t = __shfl_up(incl, off);
      if (lane >= off) incl += t;
    }
    bpre_s[lane] = incl - v;
  }
  __syncthreads();
  int t = blockIdx.x * blockDim.x + threadIdx.x;
  if (t < n) {
    int r = rowptr[t] + bpre_s[t >> 10];
    rowptr[t] = r;
#pragma unroll
    for (int c = 0; c < NC; ++c) {
      cursor[c * n + t] = r;
      r += partial[c * n + t];
    }
  }
  if (t == 0) rowptr[n] = E;
}

// fill (NO atomics): ew = sigmoid(p[s]+q[t]+b);
// edata[cursor_base+rank] = (src:u16 | bf16(ew)<<16)  -- 4B packed record
__global__ __launch_bounds__(256) void k_fill(const int* __restrict__ src,
                                              const int* __restrict__ tgt,
                                              const int* __restrict__ rank,
                                              const int* __restrict__ cursor,
                                              const float* __restrict__ p,
                                              const float* __restrict__ q,
                                              const float* __restrict__ b_pred,
                                              unsigned int* __restrict__ edata,
                                              int E, int n) {
  int e = blockIdx.x * blockDim.x + threadIdx.x;
  if (e >= E) return;
  int s = src[e], t = tgt[e];
  int c = (e >> 8) & (NC - 1);
  int pos = cursor[c * n + t] + rank[e];
  float z = p[s] + q[t] + b_pred[0];
  float w = 1.0f / (1.0f + expf(-z));
  edata[pos] = (unsigned int)s | (bf16_round(w) << 16);  // n < 65536 fits u16
}

// MFMA GEMM + fused dis: per wave, 4 lanes/row segmented-sum edata -> dis in
// register, then xwh = bf16( dis[row] * (xbh @ W) ). Also writes dis.
__global__ __launch_bounds__(256) void k_gemm_mfma(const short* __restrict__ xbh,
                                                   const short* __restrict__ wt,
                                                   const int* __restrict__ rowptr,
                                                   const unsigned int* __restrict__ edata,
                                                   float* __restrict__ dis,
                                                   unsigned int* __restrict__ xwh, int n) {
  __shared__ float cbuf[4][16 * 128];  // 32 KB
  int wave = threadIdx.x >> 6;
  int lane = threadIdx.x & 63;
  int row0 = blockIdx.x * 64 + wave * 16;

  // ---- dis for this wave's 16 rows (4 lanes per row) ----
  int rr = lane >> 2, jj = lane & 3;
  int grow = row0 + rr;
  float dv = 0.0f;
  if (grow < n) {
    int beg = rowptr[grow], end = rowptr[grow + 1];
    float sum = 0.0f;
    for (int j = beg + jj; j < end; j += 4) sum += bf_hi(edata[j]);
    sum += __shfl_xor(sum, 1);
    sum += __shfl_xor(sum, 2);
    float d = 1.0f + sum;
    dv = (d > 0.0f) ? rsqrtf(d) : 0.0f;
    if (jj == 0) dis[grow] = dv;
  }

  // ---- MFMA ----
  int rA = lane & 15, quad = lane >> 4;
  f32x4 acc[8];
#pragma unroll
  for (int cb = 0; cb < 8; ++cb) acc[cb] = (f32x4){0.f, 0.f, 0.f, 0.f};

  const short* arow = xbh + (size_t)(row0 + rA) * 128 + quad * 8;
  bool arow_ok = (row0 + rA) < n;
#pragma unroll
  for (int kk = 0; kk < 4; ++kk) {
    bf16x8 a;
    if (arow_ok) a = *(const bf16x8*)(arow + kk * 32);
    else a = (bf16x8){0, 0, 0, 0, 0, 0, 0, 0};
#pragma unroll
    for (int cb = 0; cb < 8; ++cb) {
      bf16x8 bf = *(const bf16x8*)(wt + (size_t)(cb * 16 + rA) * 128 + kk * 32 + quad * 8);
      acc[cb] = __builtin_amdgcn_mfma_f32_16x16x32_bf16(a, bf, acc[cb], 0, 0, 0);
    }
  }

  // C/D layout: col = cb*16 + (lane&15), row = quad*4 + reg
#pragma unroll
  for (int cb = 0; cb < 8; ++cb)
#pragma unroll
    for (int r = 0; r < 4; ++r)
      cbuf[wave][(quad * 4 + r) * 128 + cb * 16 + rA] = acc[cb][r];
  __syncthreads();

  int ch = jj * 32;                // col chunk of 32 (jj = lane&3)
  if (grow < n) {
    const float* cr = &cbuf[wave][rr * 128 + ch];
#pragma unroll
    for (int g = 0; g < 2; ++g) {  // 2 x 16 cols -> 2 x uint4
      uint4 o;
      o.x = bf16_round(cr[g * 16 + 0] * dv)  | (bf16_round(cr[g * 16 + 1] * dv) << 16);
      o.y = bf16_round(cr[g * 16 + 2] * dv)  | (bf16_round(cr[g * 16 + 3] * dv) << 16);
      o.z = bf16_round(cr[g * 16 + 4] * dv)  | (bf16_round(cr[g * 16 + 5] * dv) << 16);
      o.w = bf16_round(cr[g * 16 + 6] * dv)  | (bf16_round(cr[g * 16 + 7] * dv) << 16);
      uint4 o2;
      o2.x = bf16_round(cr[g * 16 + 8] * dv)  | (bf16_round(cr[g * 16 + 9] * dv) << 16);
      o2.y = bf16_round(cr[g * 16 + 10] * dv) | (bf16_round(cr[g * 16 + 11] * dv) << 16);
      o2.z = bf16_round(cr[g * 16 + 12] * dv) | (bf16_round(cr[g * 16 + 13] * dv) << 16);
      o2.w = bf16_round(cr[g * 16 + 14] * dv) | (bf16_round(cr[g * 16 + 15] * dv) << 16);
      *(uint4*)(xwh + (size_t)grow * 64 + (ch >> 1) + g * 8)     = o;
      *(uint4*)(xwh + (size_t)grow * 64 + (ch >> 1) + g * 8 + 4) = o2;
    }
  }
}

// One wave per node; lane = (rg in [0,4), cj in [0,16)). ILP-batched: per
// 16-edge group, all 4 shuffle-extracts and all 4 scattered uint4 loads issue
// before the FMA block (R11 profile showed VGPR=20 -> serial load-use chain).
__global__ __launch_bounds__(256) void k_gather(const int* __restrict__ rowptr,
                                                const unsigned int* __restrict__ edata,
                                                const uint4* __restrict__ xwh4,
                                                const float* __restrict__ dis,
                                                const float* __restrict__ b,
                                                float* __restrict__ out, int n) {
  int wid = (blockIdx.x * blockDim.x + threadIdx.x) >> 6;
  int lane = threadIdx.x & 63;
  if (wid >= n) return;
  int cj = lane & 15;
  int rg = lane >> 4;
  int2 rp = *(const int2*)(rowptr + wid);
  int beg = rp.x, end = rp.y;

  float acc[8];
  if (rg == 0) {  // self-loop term, counted once
    uint4 v = xwh4[(size_t)wid * 16 + cj];
    acc[0] = bf_lo(v.x); acc[1] = bf_hi(v.x);
    acc[2] = bf_lo(v.y); acc[3] = bf_hi(v.y);
    acc[4] = bf_lo(v.z); acc[5] = bf_hi(v.z);
    acc[6] = bf_lo(v.w); acc[7] = bf_hi(v.w);
  } else {
#pragma unroll
    for (int i = 0; i < 8; ++i) acc[i] = 0.0f;
  }

  for (int j0 = beg; j0 < end; j0 += 64) {
    int m = end - j0; if (m > 64) m = 64;
    unsigned int wl = 0;
    if (lane < m) wl = edata[j0 + lane];
    for (int k = 0; k < m; k += 16) {
      // extract 4 records (independent shfls), zero-guard tails
      unsigned int w0 = (unsigned int)__shfl((int)wl, k + rg);
      unsigned int w1 = (unsigned int)__shfl((int)wl, k + 4 + rg);
      unsigned int w2 = (unsigned int)__shfl((int)wl, k + 8 + rg);
      unsigned int w3 = (unsigned int)__shfl((int)wl, k + 12 + rg);
      if (k + rg >= m)      w0 = 0;  // s=0, c=+0.0 -> harmless
      if (k + 4 + rg >= m)  w1 = 0;
      if (k + 8 + rg >= m)  w2 = 0;
      if (k + 12 + rg >= m) w3 = 0;
      // issue all 4 scattered loads back-to-back (overlapping latencies)
      uint4 v0 = xwh4[(size_t)(w0 & 0xffffu) * 16 + cj];
      uint4 v1 = xwh4[(size_t)(w1 & 0xffffu) * 16 + cj];
      uint4 v2 = xwh4[(size_t)(w2 & 0xffffu) * 16 + cj];
      uint4 v3 = xwh4[(size_t)(w3 & 0xffffu) * 16 + cj];
      float c0 = bf_hi(w0), c1 = bf_hi(w1), c2 = bf_hi(w2), c3 = bf_hi(w3);
      acc[0] = fmaf(c0, bf_lo(v0.x), acc[0]); acc[1] = fmaf(c0, bf_hi(v0.x), acc[1]);
      acc[2] = fmaf(c0, bf_lo(v0.y), acc[2]); acc[3] = fmaf(c0, bf_hi(v0.y), acc[3]);
      acc[4] = fmaf(c0, bf_lo(v0.z), acc[4]); acc[5] = fmaf(c0, bf_hi(v0.z), acc[5]);
      acc[6] = fmaf(c0, bf_lo(v0.w), acc[6]); acc[7] = fmaf(c0, bf_hi(v0.w), acc[7]);
      acc[0] = fmaf(c1, bf_lo(v1.x), acc[0]); acc[1] = fmaf(c1, bf_hi(v1.x), acc[1]);
      acc[2] = fmaf(c1, bf_lo(v1.y), acc[2]); acc[3] = fmaf(c1, bf_hi(v1.y), acc[3]);
      acc[4] = fmaf(c1, bf_lo(v1.z), acc[4]); acc[5] = fmaf(c1, bf_hi(v1.z), acc[5]);
      acc[6] = fmaf(c1, bf_lo(v1.w), acc[6]); acc[7] = fmaf(c1, bf_hi(v1.w), acc[7]);
      acc[0] = fmaf(c2, bf_lo(v2.x), acc[0]); acc[1] = fmaf(c2, bf_hi(v2.x), acc[1]);
      acc[2] = fmaf(c2, bf_lo(v2.y), acc[2]); acc[3] = fmaf(c2, bf_hi(v2.y), acc[3]);
      acc[4] = fmaf(c2, bf_lo(v2.z), acc[4]); acc[5] = fmaf(c2, bf_hi(v2.z), acc[5]);
      acc[6] = fmaf(c2, bf_lo(v2.w), acc[6]); acc[7] = fmaf(c2, bf_hi(v2.w), acc[7]);
      acc[0] = fmaf(c3, bf_lo(v3.x), acc[0]); acc[1] = fmaf(c3, bf_hi(v3.x), acc[1]);
      acc[2] = fmaf(c3, bf_lo(v3.y), acc[2]); acc[3] = fmaf(c3, bf_hi(v3.y), acc[3]);
      acc[4] = fmaf(c3, bf_lo(v3.z), acc[4]); acc[5] = fmaf(c3, bf_hi(v3.z), acc[5]);
      acc[6] = fmaf(c3, bf_lo(v3.w), acc[6]); acc[7] = fmaf(c3, bf_hi(v3.w), acc[7]);
    }
  }

#pragma unroll
  for (int i = 0; i < 8; ++i) {
    acc[i] += __shfl_xor(acc[i], 16);
    acc[i] += __shfl_xor(acc[i], 32);
  }

  if (rg == 0) {
    float dt = dis[wid];
    float4 b0 = ((const float4*)b)[cj * 2];
    float4 b1 = ((const float4*)b)[cj * 2 + 1];
    float4 o0, o1;
    o0.x = fmaf(dt, acc[0], b0.x); o0.y = fmaf(dt, acc[1], b0.y);
    o0.z = fmaf(dt, acc[2], b0.z); o0.w = fmaf(dt, acc[3], b0.w);
    o1.x = fmaf(dt, acc[4], b1.x); o1.y = fmaf(dt, acc[5], b1.y);
    o1.z = fmaf(dt, acc[6], b1.z); o1.w = fmaf(dt, acc[7], b1.w);
    ((float4*)out)[(size_t)wid * 32 + cj * 2] = o0;
    ((float4*)out)[(size_t)wid * 32 + cj * 2 + 1] = o1;
  }
}

extern "C" void kernel_launch(void* const* d_in, const int* in_sizes, int n_in,
                              void* d_out, int out_size, void* d_ws, size_t ws_size,
                              hipStream_t stream) {
  const float* x      = (const float*)d_in[0];
  const int*   ei     = (const int*)d_in[1];
  const float* W      = (const float*)d_in[2];
  const float* b      = (const float*)d_in[3];
  const float* w_pred = (const float*)d_in[4];
  const float* b_pred = (const float*)d_in[5];

  int n = in_sizes[0] / D;
  int E = in_sizes[1] / 2;
  const int* src = ei;       // edge_index[0]
  const int* tgt = ei + E;   // edge_index[1]

  float* out = (float*)d_out;
  float* ws  = (float*)d_ws;
  // workspace layout (4B words)
  unsigned int* xwh = (unsigned int*)ws;           // n*64 (bf16 pairs)
  unsigned int* xbh = xwh + (size_t)n * 64;        // n*64 (bf16 pairs of x)
  float* p       = (float*)(xbh + (size_t)n * 64); // n
  float* q       = p + n;                          // n
  float* dis     = q + n;                          // n
  unsigned int* edata = (unsigned int*)(dis + n);  // E packed (src|ew)
  int*   rank    = (int*)(edata + E);              // E
  int*   partial = rank + E;                       // NC*n
  int*   cursor  = partial + (size_t)NC * n;       // NC*n
  int*   rowptr  = cursor + (size_t)NC * n;        // n+1
  int*   bsum    = rowptr + n + 1;                 // 64
  unsigned short* wt = (unsigned short*)(bsum + 64);  // 16384 shorts

  int nb = (n + 1023) / 1024;     // scan blocks (<=64 for n<=65536)
  int nbPq = (n + 3) / 4;
  int nbHist = (E + 255) / 256;
  int total = nbPq + nbHist;

  (void)hipMemsetAsync(partial, 0, (size_t)NC * n * sizeof(int), stream);
  k_pre<<<total, 256, 0, stream>>>(x, w_pred, W, tgt, p, q, xbh, wt, rank, partial,
                                   n, E, nbHist, total);
  k_scan1<<<nb, 256, 0, stream>>>(partial, rowptr, bsum, n);
  k_cursors<<<(n + 255) / 256, 256, 0, stream>>>(rowptr, bsum, partial, cursor, n, E, nb);
  k_fill<<<(E + 255) / 256, 256, 0, stream>>>(src, tgt, rank, cursor, p, q, b_pred, edata, E, n);
  k_gemm_mfma<<<(n + 63) / 64, 256, 0, stream>>>((const short*)xbh, (const short*)wt,
                                                 rowptr, edata, dis, xwh, n);
  k_gather<<<(n + 3) / 4, 256, 0, stream>>>(rowptr, edata, (const uint4*)xwh, dis, b, out, n);
}